// Round 3
// baseline (165.986 us; speedup 1.0000x reference)
//
#include <hip/hip_runtime.h>
#include <math.h>

#define NB   8
#define NH   3
#define NBH  (NB * NH)          // 24
#define NP   4096
#define BLK  256
#define RPT  8                  // rows per thread (2048 rows per block)
#define CQ   8                  // column quarters per (dir,bh,rowtile) group
#define RT   2                  // row tiles
#define CTILE (NP / CQ)         // 512 columns staged per block
#define WS_ENTRIES (2 * NBH * NP)   // 196608 row-min slots
#define NGROUP (2 * NBH * RT)       // 96 arrival counters

// ---- ordered-int encoding so unsigned atomicMin == float min ----
__device__ __forceinline__ unsigned enc(float f) {
    unsigned u = __float_as_uint(f);
    return (u & 0x80000000u) ? ~u : (u | 0x80000000u);
}
__device__ __forceinline__ float dec(unsigned u) {
    u = (u & 0x80000000u) ? (u & 0x7FFFFFFFu) : ~u;
    return __uint_as_float(u);
}

// out[0] = 25 * sum_b || N_b N_b^T - I ||_F   (plain store; runs before chamfer adds)
__global__ void reg_kernel(const float* __restrict__ planes, float* __restrict__ out) {
    int b = threadIdx.x;
    float r = 0.0f;
    if (b < NB) {
        float n[NH][3];
        for (int h = 0; h < NH; ++h) {
            const float* pl = planes + (b * NH + h) * 4;
            float a0 = pl[0], a1 = pl[1], a2 = pl[2];
            float inv = 1.0f / sqrtf(a0 * a0 + a1 * a1 + a2 * a2);
            n[h][0] = a0 * inv; n[h][1] = a1 * inv; n[h][2] = a2 * inv;
        }
        float fro = 0.0f;
        for (int i = 0; i < NH; ++i)
            for (int j = 0; j < NH; ++j) {
                float d = n[i][0] * n[j][0] + n[i][1] * n[j][1] + n[i][2] * n[j][2]
                          - (i == j ? 1.0f : 0.0f);
                fro += d * d;
            }
        r = sqrtf(fro);
    }
    for (int o = 32; o > 0; o >>= 1) r += __shfl_down(r, o);
    if (threadIdx.x == 0) out[0] = 25.0f * r;
}

// grid: x = cq*RT + rt (16), y = bh (24), z = dir.
// Each thread owns 8 rows (stride-256); 512 columns staged in LDS as
// float4(-2c0,-2c1,-2c2,|c|^2). Per column per row: 3 fma, mins fused
// pairwise into v_min3_f32 -> 3.5 VALU instr/pair, 1 ds_read_b128 per
// 8 pairs. Partials -> atomicMin(ws); last block of each group reduces.
__global__ void __launch_bounds__(BLK) chamfer_kernel(const float* __restrict__ pts,
                                                      const float* __restrict__ planes,
                                                      unsigned* __restrict__ ws,
                                                      float* __restrict__ out) {
    __shared__ float4 qs[CTILE];
    __shared__ float wsum[BLK / 64];

    const int rt  = blockIdx.x & (RT - 1);
    const int cq  = blockIdx.x >> 1;
    const int bh  = blockIdx.y;
    const int b   = bh / NH;
    const int dir = blockIdx.z;
    const int group = (dir * NBH + bh) * RT + rt;

    const float* pl = planes + bh * 4;
    float n0 = pl[0], n1 = pl[1], n2 = pl[2], off = pl[3];
    float inv = 1.0f / sqrtf(n0 * n0 + n1 * n1 + n2 * n2);
    n0 *= inv; n1 *= inv; n2 *= inv;

    const float* bp = pts + (size_t)b * NP * 3;

    // stage 512 columns (reflected when dir==0)
    const int cbase = cq * CTILE;
    for (int i = threadIdx.x; i < CTILE; i += BLK) {
        const int q = cbase + i;
        float y0 = bp[q * 3 + 0], y1 = bp[q * 3 + 1], y2 = bp[q * 3 + 2];
        if (!dir) {
            float t = 2.0f * (n0 * y0 + n1 * y1 + n2 * y2 + off);
            y0 -= t * n0; y1 -= t * n1; y2 -= t * n2;
        }
        float ysq = y0 * y0 + y1 * y1 + y2 * y2;
        qs[i] = make_float4(-2.0f * y0, -2.0f * y1, -2.0f * y2, ysq);
    }

    // 8 row points per thread (reflected when dir==1)
    float x0[RPT], x1[RPT], x2[RPT], xsq[RPT], m[RPT];
    const int rbase = rt * (BLK * RPT) + threadIdx.x;
    #pragma unroll
    for (int k = 0; k < RPT; ++k) {
        const int r = rbase + k * BLK;
        float a0 = bp[r * 3 + 0], a1 = bp[r * 3 + 1], a2 = bp[r * 3 + 2];
        if (dir) {
            float t = 2.0f * (n0 * a0 + n1 * a1 + n2 * a2 + off);
            a0 -= t * n0; a1 -= t * n1; a2 -= t * n2;
        }
        x0[k] = a0; x1[k] = a1; x2[k] = a2;
        xsq[k] = a0 * a0 + a1 * a1 + a2 * a2;
        m[k] = 1e30f;
    }

    __syncthreads();

    for (int i = 0; i < CTILE; i += 4) {
        float4 cA = qs[i], cB = qs[i + 1], cC = qs[i + 2], cD = qs[i + 3];
        #pragma unroll
        for (int k = 0; k < RPT; ++k) {
            float tA = fmaf(x2[k], cA.z, fmaf(x1[k], cA.y, fmaf(x0[k], cA.x, cA.w)));
            float tB = fmaf(x2[k], cB.z, fmaf(x1[k], cB.y, fmaf(x0[k], cB.x, cB.w)));
            float tC = fmaf(x2[k], cC.z, fmaf(x1[k], cC.y, fmaf(x0[k], cC.x, cC.w)));
            float tD = fmaf(x2[k], cD.z, fmaf(x1[k], cD.y, fmaf(x0[k], cD.x, cD.w)));
            m[k] = fminf(fminf(m[k], tA), tB);   // v_min3_f32
            m[k] = fminf(fminf(m[k], tC), tD);   // v_min3_f32
        }
    }

    unsigned* wrow = ws + (size_t)(dir * NBH + bh) * NP;
    #pragma unroll
    for (int k = 0; k < RPT; ++k)
        atomicMin(&wrow[rbase + k * BLK], enc(xsq[k] + m[k]));

    // ---- group arrival: last of the CQ producer blocks reduces its rows ----
    __threadfence();
    __shared__ int is_last;
    if (threadIdx.x == 0) {
        unsigned* ctr = ws + WS_ENTRIES + group;
        unsigned old = atomicAdd(ctr, 1u);   // memset 0xFF: olds run -1,0,...,CQ-2
        is_last = (old == (unsigned)(CQ - 2));
    }
    __syncthreads();
    if (!is_last) return;
    __threadfence();

    const unsigned* grow = ws + (size_t)(dir * NBH + bh) * NP + rt * (BLK * RPT);
    float s = 0.0f;
    #pragma unroll
    for (int k = 0; k < RPT; ++k)
        s += fmaxf(dec(grow[threadIdx.x + k * BLK]), 0.0f);

    for (int o = 32; o > 0; o >>= 1) s += __shfl_down(s, o);
    const int wid = threadIdx.x >> 6;
    if ((threadIdx.x & 63) == 0) wsum[wid] = s;
    __syncthreads();
    if (threadIdx.x == 0) {
        float t = (wsum[0] + wsum[1] + wsum[2] + wsum[3]) * (1.0f / (float)(NB * NP));
        atomicAdd(out, t);
    }
}

extern "C" void kernel_launch(void* const* d_in, const int* in_sizes, int n_in,
                              void* d_out, int out_size, void* d_ws, size_t ws_size,
                              hipStream_t stream) {
    const float* planes = (const float*)d_in[0];  // (8,3,4) fp32
    const float* pts    = (const float*)d_in[1];  // (8,4096,3) fp32
    float* out          = (float*)d_out;
    unsigned* ws        = (unsigned*)d_ws;

    // 0xFF == +inf in ordered-int encoding; also primes counters to -1
    hipMemsetAsync(ws, 0xFF, (WS_ENTRIES + NGROUP) * sizeof(unsigned), stream);

    reg_kernel<<<1, 64, 0, stream>>>(planes, out);  // initializes out[0]

    dim3 grid(CQ * RT, NBH, 2);
    chamfer_kernel<<<grid, BLK, 0, stream>>>(pts, planes, ws, out);
}

// Round 4
// 126.305 us; speedup vs baseline: 1.3142x; 1.3142x over previous
//
#include <hip/hip_runtime.h>
#include <math.h>

#define NB 8
#define NH 3
#define NBH 24
#define NP 4096
#define BLK 256
#define RPB 128            // rows per block (4 waves x 32)
#define ROWBLKS (NP / RPB) // 32
#define NSLOTS 64

typedef _Float16 half4 __attribute__((ext_vector_type(4)));
typedef _Float16 half8 __attribute__((ext_vector_type(8)));
typedef float floatx16 __attribute__((ext_vector_type(16)));

// D = A(32x16) * B(16x32), K=4 real (rest zero in A, so B pad lanes are don't-care).
// A row r = [r0, r1, r2, 1];  B col c = [-2c0, -2c1, -2c2, csq]  ->  D = csq - 2 r.c
// row-min over cols kept in registers; d(p,q) = rsq_p + D, clamp after min (exact).
__global__ void __launch_bounds__(BLK) chamfer_mfma(const float* __restrict__ pts,
                                                    const float* __restrict__ planes,
                                                    float* __restrict__ ws) {
    __shared__ _Float16 qcols[NP * 4];   // 32 KB: per col [-2c0,-2c1,-2c2,csq]
    __shared__ float rsqbuf[RPB];

    const int tid  = threadIdx.x;
    const int lane = tid & 63;
    const int wave = tid >> 6;
    const int bh   = blockIdx.y;
    const int b    = bh / NH;
    const int dir  = blockIdx.z;

    const float* pl = planes + bh * 4;
    float n0 = pl[0], n1 = pl[1], n2 = pl[2], off = pl[3];
    float inv = 1.0f / sqrtf(n0 * n0 + n1 * n1 + n2 * n2);
    n0 *= inv; n1 *= inv; n2 *= inv;

    const float* bp = pts + (size_t)b * NP * 3;

    // stage 4096 cols (reflected when dir==0), f16, -2 folded, csq appended
    for (int i = tid; i < NP; i += BLK) {
        float y0 = bp[i * 3 + 0], y1 = bp[i * 3 + 1], y2 = bp[i * 3 + 2];
        if (!dir) { float t = 2.0f * (n0 * y0 + n1 * y1 + n2 * y2 + off); y0 -= t * n0; y1 -= t * n1; y2 -= t * n2; }
        float csq = y0 * y0 + y1 * y1 + y2 * y2;
        half4 v = { (_Float16)(-2.0f * y0), (_Float16)(-2.0f * y1),
                    (_Float16)(-2.0f * y2), (_Float16)csq };
        *(half4*)&qcols[i * 4] = v;
    }

    // A fragment: lane holds row = lane&31, k = (lane>>5)*8 + j. Only lanes<32, k<4 real.
    const int rlocal = wave * 32 + (lane & 31);
    const int row = blockIdx.x * RPB + rlocal;
    half8 afrag = {0, 0, 0, 0, 0, 0, 0, 0};
    {
        float a0 = bp[row * 3 + 0], a1 = bp[row * 3 + 1], a2 = bp[row * 3 + 2];
        if (dir) { float t = 2.0f * (n0 * a0 + n1 * a1 + n2 * a2 + off); a0 -= t * n0; a1 -= t * n1; a2 -= t * n2; }
        if (lane < 32) {
            rsqbuf[rlocal] = a0 * a0 + a1 * a1 + a2 * a2;
            afrag[0] = (_Float16)a0; afrag[1] = (_Float16)a1;
            afrag[2] = (_Float16)a2; afrag[3] = (_Float16)1.0f;
        }
    }
    __syncthreads();

    floatx16 zacc;
    #pragma unroll
    for (int j = 0; j < 16; ++j) zacc[j] = 0.0f;

    float rm[16];
    #pragma unroll
    for (int j = 0; j < 16; ++j) rm[j] = 1e30f;

    // B fragment read: lane -> col = tile*32 + (lane&31); lanes 32-63 duplicate
    // (broadcast, free) — their k=8..15 products hit A-zeros. k=4..7 also A-zeros,
    // so the upper half of the frag can be junk (reuse c0).
    const _Float16* bcol = &qcols[(lane & 31) * 4];

    for (int t = 0; t < 128; t += 2) {
        half4 c0 = *(const half4*)(bcol + (t    ) * 128);
        half4 c1 = *(const half4*)(bcol + (t + 1) * 128);
        half8 B0 = __builtin_shufflevector(c0, c0, 0, 1, 2, 3, 0, 1, 2, 3);
        half8 B1 = __builtin_shufflevector(c1, c1, 0, 1, 2, 3, 0, 1, 2, 3);
        floatx16 d0 = __builtin_amdgcn_mfma_f32_32x32x16_f16(afrag, B0, zacc, 0, 0, 0);
        floatx16 d1 = __builtin_amdgcn_mfma_f32_32x32x16_f16(afrag, B1, zacc, 0, 0, 0);
        #pragma unroll
        for (int j = 0; j < 16; ++j)
            rm[j] = fminf(rm[j], fminf(d0[j], d1[j]));   // v_min3_f32
    }

    // cross-lane min over the 32 lanes sharing each row (C/D: col=lane&31,
    // row=(reg&3)+8*(reg>>2)+4*(lane>>5))
    #pragma unroll
    for (int j = 0; j < 16; ++j) {
        float v = rm[j];
        v = fminf(v, __shfl_xor(v, 1));
        v = fminf(v, __shfl_xor(v, 2));
        v = fminf(v, __shfl_xor(v, 4));
        v = fminf(v, __shfl_xor(v, 8));
        v = fminf(v, __shfl_xor(v, 16));
        rm[j] = v;
    }
    const int h = lane >> 5;
    float s = 0.0f;
    #pragma unroll
    for (int j = 0; j < 16; ++j) {
        int rl = wave * 32 + (j & 3) + 8 * (j >> 2) + 4 * h;
        s += fmaxf(rsqbuf[rl] + rm[j], 0.0f);   // clamp after min (commutes)
    }
    s += __shfl_xor(s, 32);   // combine the two 32-lane halves (rows +0 / +4)

    if (lane == 0) {
        int slot = (((bh * ROWBLKS + blockIdx.x) * 2 + dir) * 4 + wave) & (NSLOTS - 1);
        atomicAdd(&ws[slot], s);
    }
}

// reg-loss + chamfer sum -> single store to out[0]
__global__ void final_kernel(const float* __restrict__ planes,
                             const float* __restrict__ ws,
                             float* __restrict__ out) {
    const int l = threadIdx.x;  // 64
    float v = ws[l] * (1.0f / (float)(NB * NP));
    if (l < NB) {
        float n[NH][3];
        for (int hh = 0; hh < NH; ++hh) {
            const float* pl = planes + (l * NH + hh) * 4;
            float a0 = pl[0], a1 = pl[1], a2 = pl[2];
            float inv = 1.0f / sqrtf(a0 * a0 + a1 * a1 + a2 * a2);
            n[hh][0] = a0 * inv; n[hh][1] = a1 * inv; n[hh][2] = a2 * inv;
        }
        float fro = 0.0f;
        for (int i = 0; i < NH; ++i)
            for (int j = 0; j < NH; ++j) {
                float d = n[i][0] * n[j][0] + n[i][1] * n[j][1] + n[i][2] * n[j][2]
                          - (i == j ? 1.0f : 0.0f);
                fro += d * d;
            }
        v += 25.0f * sqrtf(fro);
    }
    for (int o = 32; o; o >>= 1) v += __shfl_down(v, o);
    if (l == 0) out[0] = v;
}

extern "C" void kernel_launch(void* const* d_in, const int* in_sizes, int n_in,
                              void* d_out, int out_size, void* d_ws, size_t ws_size,
                              hipStream_t stream) {
    const float* planes = (const float*)d_in[0];  // (8,3,4) fp32
    const float* pts    = (const float*)d_in[1];  // (8,4096,3) fp32
    float* out          = (float*)d_out;
    float* ws           = (float*)d_ws;

    hipMemsetAsync(ws, 0, NSLOTS * sizeof(float), stream);

    dim3 grid(ROWBLKS, NBH, 2);
    chamfer_mfma<<<grid, BLK, 0, stream>>>(pts, planes, ws);

    final_kernel<<<1, 64, 0, stream>>>(planes, ws, out);
}

// Round 5
// 118.040 us; speedup vs baseline: 1.4062x; 1.0700x over previous
//
#include <hip/hip_runtime.h>
#include <math.h>

#define NB 8
#define NH 3
#define NBH 24
#define NP 4096
#define BLK 256
#define RPB 128            // rows per block (4 waves x 32)
#define ROWBLKS (NP / RPB) // 32

typedef _Float16 half4 __attribute__((ext_vector_type(4)));
typedef _Float16 half8 __attribute__((ext_vector_type(8)));
typedef float floatx16 __attribute__((ext_vector_type(16)));

// out[0] = 25 * sum_b || N_b N_b^T - I ||_F  (runs before chamfer's atomicAdds)
__global__ void reg_kernel(const float* __restrict__ planes, float* __restrict__ out) {
    const int l = threadIdx.x;
    float r = 0.0f;
    if (l < NB) {
        float n[NH][3];
        for (int hh = 0; hh < NH; ++hh) {
            const float* pl = planes + (l * NH + hh) * 4;
            float a0 = pl[0], a1 = pl[1], a2 = pl[2];
            float inv = 1.0f / sqrtf(a0 * a0 + a1 * a1 + a2 * a2);
            n[hh][0] = a0 * inv; n[hh][1] = a1 * inv; n[hh][2] = a2 * inv;
        }
        float fro = 0.0f;
        for (int i = 0; i < NH; ++i)
            for (int j = 0; j < NH; ++j) {
                float d = n[i][0] * n[j][0] + n[i][1] * n[j][1] + n[i][2] * n[j][2]
                          - (i == j ? 1.0f : 0.0f);
                fro += d * d;
            }
        r = 25.0f * sqrtf(fro);
    }
    for (int o = 32; o; o >>= 1) r += __shfl_down(r, o);
    if (l == 0) out[0] = r;
}

// D = A(32x16)*B(16x32) + C,  K=4 real: A row = [r0,r1,r2,1, 0...]; B col =
// [-2c0,-2c1,-2c2,csq, junk(finite)]; C = rsq(row) -> D = full distance.
// min over cols in regs (v_min3), clamp after min (exact), block-reduce,
// one atomicAdd(out) per block.
// __launch_bounds__(256,4): 128-reg budget matches the LDS cap (4 blk/CU) so
// d/rm/crsq live in VGPRs, not AGPRs (R4's VALU bloat was accvgpr round-trips).
__global__ void __launch_bounds__(BLK, 4) chamfer_mfma(const float* __restrict__ pts,
                                                       const float* __restrict__ planes,
                                                       float* __restrict__ out) {
    __shared__ _Float16 qcols[NP * 4];   // 32 KB: per col [-2c0,-2c1,-2c2,csq]
    __shared__ float rsqbuf[RPB];
    __shared__ float bsum[4];

    const int tid  = threadIdx.x;
    const int lane = tid & 63;
    const int wave = tid >> 6;
    const int bh   = blockIdx.y;
    const int b    = bh / NH;
    const int dir  = blockIdx.z;

    const float* pl = planes + bh * 4;
    float n0 = pl[0], n1 = pl[1], n2 = pl[2], off = pl[3];
    float inv = 1.0f / sqrtf(n0 * n0 + n1 * n1 + n2 * n2);
    n0 *= inv; n1 *= inv; n2 *= inv;

    const float* bp = pts + (size_t)b * NP * 3;

    // stage 4096 cols (reflected when dir==0)
    for (int i = tid; i < NP; i += BLK) {
        float y0 = bp[i * 3 + 0], y1 = bp[i * 3 + 1], y2 = bp[i * 3 + 2];
        if (!dir) { float t = 2.0f * (n0 * y0 + n1 * y1 + n2 * y2 + off); y0 -= t * n0; y1 -= t * n1; y2 -= t * n2; }
        float csq = y0 * y0 + y1 * y1 + y2 * y2;
        half4 v = { (_Float16)(-2.0f * y0), (_Float16)(-2.0f * y1),
                    (_Float16)(-2.0f * y2), (_Float16)csq };
        *(half4*)&qcols[i * 4] = v;
    }

    // A fragment: lane m = lane&31, k = (lane>>5)*8 + j; only lanes<32, k<4 real
    const int rlocal = wave * 32 + (lane & 31);
    const int row = blockIdx.x * RPB + rlocal;
    half8 afrag = {0, 0, 0, 0, 0, 0, 0, 0};
    {
        float a0 = bp[row * 3 + 0], a1 = bp[row * 3 + 1], a2 = bp[row * 3 + 2];
        if (dir) { float t = 2.0f * (n0 * a0 + n1 * a1 + n2 * a2 + off); a0 -= t * n0; a1 -= t * n1; a2 -= t * n2; }
        if (lane < 32) {
            rsqbuf[rlocal] = a0 * a0 + a1 * a1 + a2 * a2;
            afrag[0] = (_Float16)a0; afrag[1] = (_Float16)a1;
            afrag[2] = (_Float16)a2; afrag[3] = (_Float16)1.0f;
        }
    }
    __syncthreads();

    // C fragment: rsq of each output row (C/D: col=lane&31, row=(j&3)+8*(j>>2)+4*(lane>>5))
    const int h = lane >> 5;
    floatx16 crsq;
    #pragma unroll
    for (int j = 0; j < 16; ++j)
        crsq[j] = rsqbuf[wave * 32 + (j & 3) + 8 * (j >> 2) + 4 * h];

    floatx16 rm;
    #pragma unroll
    for (int j = 0; j < 16; ++j) rm[j] = 1e30f;

    // B frag: lane n = lane&31 -> col t*32+n; lanes 32-63 duplicate (broadcast);
    // k>=4 half reuses the col's own data (finite junk x A-zero = 0).
    const _Float16* bcol = &qcols[(lane & 31) * 4];

    #pragma unroll 2
    for (int t = 0; t < 128; t += 2) {
        half4 c0 = *(const half4*)(bcol + (t    ) * 128);
        half4 c1 = *(const half4*)(bcol + (t + 1) * 128);
        half8 B0 = __builtin_shufflevector(c0, c0, 0, 1, 2, 3, 0, 1, 2, 3);
        half8 B1 = __builtin_shufflevector(c1, c1, 0, 1, 2, 3, 0, 1, 2, 3);
        floatx16 d0 = __builtin_amdgcn_mfma_f32_32x32x16_f16(afrag, B0, crsq, 0, 0, 0);
        floatx16 d1 = __builtin_amdgcn_mfma_f32_32x32x16_f16(afrag, B1, crsq, 0, 0, 0);
        #pragma unroll
        for (int j = 0; j < 16; ++j)
            rm[j] = fminf(rm[j], fminf(d0[j], d1[j]));   // v_min3_f32
    }

    // min across the 32 lanes sharing each row, then clamp + sum per half
    #pragma unroll
    for (int j = 0; j < 16; ++j) {
        float v = rm[j];
        v = fminf(v, __shfl_xor(v, 1));
        v = fminf(v, __shfl_xor(v, 2));
        v = fminf(v, __shfl_xor(v, 4));
        v = fminf(v, __shfl_xor(v, 8));
        v = fminf(v, __shfl_xor(v, 16));
        rm[j] = v;
    }
    float s = 0.0f;
    #pragma unroll
    for (int j = 0; j < 16; ++j) s += fmaxf(rm[j], 0.0f);  // clamp after min (exact)
    s += __shfl_xor(s, 32);   // combine the two 16-row halves of the wave

    if (lane == 0) bsum[wave] = s;
    __syncthreads();
    if (tid == 0)
        atomicAdd(out, (bsum[0] + bsum[1] + bsum[2] + bsum[3]) * (1.0f / (float)(NB * NP)));
}

extern "C" void kernel_launch(void* const* d_in, const int* in_sizes, int n_in,
                              void* d_out, int out_size, void* d_ws, size_t ws_size,
                              hipStream_t stream) {
    const float* planes = (const float*)d_in[0];  // (8,3,4) fp32
    const float* pts    = (const float*)d_in[1];  // (8,4096,3) fp32
    float* out          = (float*)d_out;

    reg_kernel<<<1, 64, 0, stream>>>(planes, out);   // initializes out[0]

    dim3 grid(ROWBLKS, NBH, 2);
    chamfer_mfma<<<grid, BLK, 0, stream>>>(pts, planes, out);
}

// Round 6
// 97.713 us; speedup vs baseline: 1.6987x; 1.2080x over previous
//
#include <hip/hip_runtime.h>
#include <math.h>

#define NB 8
#define NH 3
#define NBH 24
#define NP 4096
#define BLK 256
#define RPB 128            // rows per block (4 waves x 32)
#define ROWBLKS (NP / RPB) // 32

typedef _Float16 half4 __attribute__((ext_vector_type(4)));
typedef _Float16 half8 __attribute__((ext_vector_type(8)));
typedef float floatx16 __attribute__((ext_vector_type(16)));

// Forced v_min3_f32: guarantees the 3-input fuse (no -ffast-math, so the
// compiler won't do it) AND forces a,b (MFMA results) into VGPRs — the RA
// would otherwise park them in AGPRs and pay v_accvgpr_read per element.
#define MIN3(r, a, b) asm("v_min3_f32 %0, %0, %1, %2" : "+v"(r) : "v"(a), "v"(b))

// out[0] = 25 * sum_b || N_b N_b^T - I ||_F  (plain store; runs before chamfer adds)
__global__ void reg_kernel(const float* __restrict__ planes, float* __restrict__ out) {
    const int l = threadIdx.x;
    float r = 0.0f;
    if (l < NB) {
        float n[NH][3];
        for (int hh = 0; hh < NH; ++hh) {
            const float* pl = planes + (l * NH + hh) * 4;
            float a0 = pl[0], a1 = pl[1], a2 = pl[2];
            float inv = 1.0f / sqrtf(a0 * a0 + a1 * a1 + a2 * a2);
            n[hh][0] = a0 * inv; n[hh][1] = a1 * inv; n[hh][2] = a2 * inv;
        }
        float fro = 0.0f;
        for (int i = 0; i < NH; ++i)
            for (int j = 0; j < NH; ++j) {
                float d = n[i][0] * n[j][0] + n[i][1] * n[j][1] + n[i][2] * n[j][2]
                          - (i == j ? 1.0f : 0.0f);
                fro += d * d;
            }
        r = 25.0f * sqrtf(fro);
    }
    for (int o = 32; o; o >>= 1) r += __shfl_down(r, o);
    if (l == 0) out[0] = r;
}

// D = A(32x16)*B(16x32) + C,  K=4 real: A row = [r0,r1,r2,1, 0...]; B col =
// [-2c0,-2c1,-2c2,csq, zeros]; C = rsq(row) -> D = full squared distance.
// Row-min over cols via forced v_min3 in VGPRs; clamp after min (exact);
// block-reduce; one atomicAdd(out) per block.
__global__ void __launch_bounds__(BLK, 4) chamfer_mfma(const float* __restrict__ pts,
                                                       const float* __restrict__ planes,
                                                       float* __restrict__ out) {
    __shared__ _Float16 qcols[NP * 4];   // 32 KB: per col [-2c0,-2c1,-2c2,csq]
    __shared__ float rsqbuf[RPB];
    __shared__ float bsum[4];

    const int tid  = threadIdx.x;
    const int lane = tid & 63;
    const int wave = tid >> 6;
    const int bh   = blockIdx.y;
    const int b    = bh / NH;
    const int dir  = blockIdx.z;

    const float* pl = planes + bh * 4;
    float n0 = pl[0], n1 = pl[1], n2 = pl[2], off = pl[3];
    float inv = 1.0f / sqrtf(n0 * n0 + n1 * n1 + n2 * n2);
    n0 *= inv; n1 *= inv; n2 *= inv;

    const float* bp = pts + (size_t)b * NP * 3;

    // stage 4096 cols (reflected when dir==0)
    for (int i = tid; i < NP; i += BLK) {
        float y0 = bp[i * 3 + 0], y1 = bp[i * 3 + 1], y2 = bp[i * 3 + 2];
        if (!dir) { float t = 2.0f * (n0 * y0 + n1 * y1 + n2 * y2 + off); y0 -= t * n0; y1 -= t * n1; y2 -= t * n2; }
        float csq = y0 * y0 + y1 * y1 + y2 * y2;
        half4 v = { (_Float16)(-2.0f * y0), (_Float16)(-2.0f * y1),
                    (_Float16)(-2.0f * y2), (_Float16)csq };
        *(half4*)&qcols[i * 4] = v;
    }

    // A fragment: lane m = lane&31, k = (lane>>5)*8 + j; only lanes<32, k<4 real
    const int rlocal = wave * 32 + (lane & 31);
    const int row = blockIdx.x * RPB + rlocal;
    half8 afrag = {0, 0, 0, 0, 0, 0, 0, 0};
    {
        float a0 = bp[row * 3 + 0], a1 = bp[row * 3 + 1], a2 = bp[row * 3 + 2];
        if (dir) { float t = 2.0f * (n0 * a0 + n1 * a1 + n2 * a2 + off); a0 -= t * n0; a1 -= t * n1; a2 -= t * n2; }
        if (lane < 32) {
            rsqbuf[rlocal] = a0 * a0 + a1 * a1 + a2 * a2;
            afrag[0] = (_Float16)a0; afrag[1] = (_Float16)a1;
            afrag[2] = (_Float16)a2; afrag[3] = (_Float16)1.0f;
        }
    }
    __syncthreads();

    // C fragment: rsq of each output row (C/D: col=lane&31, row=(j&3)+8*(j>>2)+4*(lane>>5))
    const int h = lane >> 5;
    floatx16 crsq;
    #pragma unroll
    for (int j = 0; j < 16; ++j)
        crsq[j] = rsqbuf[wave * 32 + (j & 3) + 8 * (j >> 2) + 4 * h];

    float rm[16];
    #pragma unroll
    for (int j = 0; j < 16; ++j) rm[j] = 1e30f;

    // B frag: lane n = lane&31 -> col t*32+n; lanes 32-63 duplicate (broadcast);
    // k>=4 half = zeros (A is zero there anyway; zeros keep products finite).
    const _Float16* bcol = &qcols[(lane & 31) * 4];
    const half4 z4 = {(_Float16)0.0f, (_Float16)0.0f, (_Float16)0.0f, (_Float16)0.0f};

    #pragma unroll 4
    for (int t = 0; t < 128; t += 2) {
        half4 c0 = *(const half4*)(bcol + (t    ) * 128);
        half4 c1 = *(const half4*)(bcol + (t + 1) * 128);
        half8 B0 = __builtin_shufflevector(c0, z4, 0, 1, 2, 3, 4, 5, 6, 7);
        half8 B1 = __builtin_shufflevector(c1, z4, 0, 1, 2, 3, 4, 5, 6, 7);
        floatx16 d0 = __builtin_amdgcn_mfma_f32_32x32x16_f16(afrag, B0, crsq, 0, 0, 0);
        floatx16 d1 = __builtin_amdgcn_mfma_f32_32x32x16_f16(afrag, B1, crsq, 0, 0, 0);
        #pragma unroll
        for (int j = 0; j < 16; ++j)
            MIN3(rm[j], d0[j], d1[j]);
    }

    // min across the 32 lanes sharing each row, then clamp + sum per half
    #pragma unroll
    for (int j = 0; j < 16; ++j) {
        float v = rm[j];
        v = fminf(v, __shfl_xor(v, 1));
        v = fminf(v, __shfl_xor(v, 2));
        v = fminf(v, __shfl_xor(v, 4));
        v = fminf(v, __shfl_xor(v, 8));
        v = fminf(v, __shfl_xor(v, 16));
        rm[j] = v;
    }
    float s = 0.0f;
    #pragma unroll
    for (int j = 0; j < 16; ++j) s += fmaxf(rm[j], 0.0f);  // clamp after min (exact)
    s += __shfl_xor(s, 32);   // combine the two 16-row halves of the wave

    if (lane == 0) bsum[wave] = s;
    __syncthreads();
    if (tid == 0)
        atomicAdd(out, (bsum[0] + bsum[1] + bsum[2] + bsum[3]) * (1.0f / (float)(NB * NP)));
}

extern "C" void kernel_launch(void* const* d_in, const int* in_sizes, int n_in,
                              void* d_out, int out_size, void* d_ws, size_t ws_size,
                              hipStream_t stream) {
    const float* planes = (const float*)d_in[0];  // (8,3,4) fp32
    const float* pts    = (const float*)d_in[1];  // (8,4096,3) fp32
    float* out          = (float*)d_out;

    reg_kernel<<<1, 64, 0, stream>>>(planes, out);   // initializes out[0]

    dim3 grid(ROWBLKS, NBH, 2);
    chamfer_mfma<<<grid, BLK, 0, stream>>>(pts, planes, out);
}